// Round 15
// baseline (216.841 us; speedup 1.0000x reference)
//
#include <hip/hip_runtime.h>
#include <hip/hip_bf16.h>

typedef __attribute__((ext_vector_type(8))) short bf16x8;
typedef __attribute__((ext_vector_type(4))) float f32x4;

__device__ __forceinline__ float b2f(unsigned short u) {
  union { unsigned int i; float f; } x; x.i = ((unsigned int)u) << 16; return x.f;
}
__device__ __forceinline__ unsigned short f2b(float f) {
  union { __hip_bfloat16 h; unsigned short u; } x; x.h = __float2bfloat16(f); return x.u;
}
__device__ __forceinline__ f32x4 mfma16(bf16x8 a, bf16x8 b, f32x4 c) {
  return __builtin_amdgcn_mfma_f32_16x16x32_bf16(a, b, c, 0, 0, 0);
}
__device__ __forceinline__ void gl16(const void* g, void* l) {
  __builtin_amdgcn_global_load_lds(
      (const __attribute__((address_space(1))) unsigned int*)g,
      (__attribute__((address_space(3))) unsigned int*)l, 16, 0, 0);
}

// ---- ALL casts + ksum zero in ONE dispatch: x (16384 blks), 4 weights (4096), ksum (1) ----
__global__ __launch_bounds__(256) void cast_all(
    const float* __restrict__ x,
    const float* __restrict__ s0, const float* __restrict__ s1,
    const float* __restrict__ s2, const float* __restrict__ s3,
    unsigned short* __restrict__ xb,
    unsigned short* __restrict__ d0, unsigned short* __restrict__ d1,
    unsigned short* __restrict__ d2, unsigned short* __restrict__ d3,
    float* __restrict__ ksum) {
  int bid = blockIdx.x;
  if (bid < 16384) {
    int i = bid * 256 + threadIdx.x;
    float4 v = ((const float4*)x)[i];
    ushort4 o;
    o.x = f2b(v.x); o.y = f2b(v.y); o.z = f2b(v.z); o.w = f2b(v.w);
    ((ushort4*)xb)[i] = o;
  } else if (bid < 20480) {
    int r = bid - 16384;
    int seg = r >> 10;
    int i = (r & 1023) * 256 + threadIdx.x;
    const float* s = (seg == 0) ? s0 : (seg == 1) ? s1 : (seg == 2) ? s2 : s3;
    unsigned short* d = (seg == 0) ? d0 : (seg == 1) ? d1 : (seg == 2) ? d2 : d3;
    float4 v = ((const float4*)s)[i];
    ushort4 o;
    o.x = f2b(v.x); o.y = f2b(v.y); o.z = f2b(v.z); o.w = f2b(v.w);
    ((ushort4*)d)[i] = o;
  } else {
    ((float4*)ksum)[threadIdx.x * 4 + 0] = make_float4(0.f, 0.f, 0.f, 0.f);
    ((float4*)ksum)[threadIdx.x * 4 + 1] = make_float4(0.f, 0.f, 0.f, 0.f);
    ((float4*)ksum)[threadIdx.x * 4 + 2] = make_float4(0.f, 0.f, 0.f, 0.f);
    ((float4*)ksum)[threadIdx.x * 4 + 3] = make_float4(0.f, 0.f, 0.f, 0.f);
  }
}

// =============== 256x256 bf16 GEMM (C = A * W^T), K=1024 ===============
// R15 = R14 resubmitted unchanged (infra failure; code never ran).
// R14 CHANGE (single variable vs R13): LGKM0 moved from BEFORE the MFMA
// cluster to AFTER it (just before the barrier). The early full drain forced
// the first MFMA to wait for ALL 12-16 ds_reads; with it removed, the
// compiler's waitcnt pass inserts PRECISE partial lgkmcnt waits per fragment
// (documented m97 behavior), overlapping the LDS read stream with the MFMA
// drain inside each phase. LGKM0's WAR role (reads retired before the
// trailing barrier licenses re-stages) is preserved at its new position.
// vmcnt FIFO ledger unchanged from R13:
//   P2-WAITV4 drains prevP4 + P1 stages -> P3 reads safe.
//   P4-WAITV4 drains P2 + P3 stages -> next-P1 reads safe.
#define BARX() __builtin_amdgcn_s_barrier()
#define LGKM0() asm volatile("s_waitcnt lgkmcnt(0)")
#define WAITV4() asm volatile("s_waitcnt vmcnt(4)")
#define WAITV0() asm volatile("s_waitcnt vmcnt(0)" ::: "memory")
#define P1() __builtin_amdgcn_s_setprio(1)
#define P0() __builtin_amdgcn_s_setprio(0)

#define STAGE_A(BUF, G, TAU) do { \
  gl16(gA_0 + (size_t)(G) * 65536 + (TAU) * 64, sAB + (BUF) * 32768 + (G) * 16384 + u0 * 16); \
  gl16(gA_1 + (size_t)(G) * 65536 + (TAU) * 64, sAB + (BUF) * 32768 + (G) * 16384 + u1 * 16); } while (0)
#define STAGE_B(BUF, G, TAU) do { \
  gl16(gB_0 + (size_t)(G) * 32768 + (TAU) * 64, sAB + 65536 + (BUF) * 32768 + (G) * 16384 + u0 * 16); \
  gl16(gB_1 + (size_t)(G) * 32768 + (TAU) * 64, sAB + 65536 + (BUF) * 32768 + (G) * 16384 + u1 * 16); } while (0)

#define LOAD_A(BUF, MH) do { \
  _Pragma("unroll") for (int mi = 0; mi < 4; ++mi) { \
    const char* p_ = (const char*)sAB + (BUF) * 32768 + (MH) * 16384 + aRd + mi * 2048; \
    af[mi][0] = *(const bf16x8*)(p_ + sr0); \
    af[mi][1] = *(const bf16x8*)(p_ + sr1); } } while (0)
#define LOAD_B(BUF, NH, DST) do { \
  _Pragma("unroll") for (int ni = 0; ni < 2; ++ni) { \
    const char* p_ = (const char*)sAB + 65536 + (BUF) * 32768 + (NH) * 16384 + bRd + ni * 2048; \
    DST[ni][0] = *(const bf16x8*)(p_ + sr0); \
    DST[ni][1] = *(const bf16x8*)(p_ + sr1); } } while (0)

#define QUAD(MH, NH, BF) do { \
  _Pragma("unroll") for (int mi = 0; mi < 4; ++mi) \
    _Pragma("unroll") for (int ni = 0; ni < 2; ++ni) { \
      acc[(MH) * 4 + mi][(NH) * 2 + ni] = mfma16(af[mi][0], BF[ni][0], acc[(MH) * 4 + mi][(NH) * 2 + ni]); \
      acc[(MH) * 4 + mi][(NH) * 2 + ni] = mfma16(af[mi][1], BF[ni][1], acc[(MH) * 4 + mi][(NH) * 2 + ni]); } } while (0)

template<int MODE>
__global__ __launch_bounds__(512, 2) void gemm256(
    const unsigned short* __restrict__ A,
    const unsigned short* __restrict__ W0, const unsigned short* __restrict__ W1,
    const unsigned short* __restrict__ W2,
    const float* __restrict__ bias0, const float* __restrict__ bias1, const float* __restrict__ bias2,
    float* __restrict__ outF,
    unsigned short* __restrict__ o0, unsigned short* __restrict__ o1, unsigned short* __restrict__ o2,
    int tiles_n, float* __restrict__ ksum)
{
  __shared__ char sAB[131072];
  int bid = blockIdx.x;
  int nwg = gridDim.x;
  int cpx = nwg >> 3;                       // nwg % 8 == 0 for all launches
  int sbid = (bid & 7) * cpx + (bid >> 3);  // XCD-aware swizzle (bijective)
  int tn = sbid % tiles_n, tm = sbid / tiles_n;  // tm-major within XCD
  int m0 = tm * 256, n0 = tn * 256;

  const unsigned short* W = W0; const float* bias = bias0; unsigned short* outB = o0;
  int sel = 0;
  if (MODE == 1) {
    sel = n0 >> 10;
    if (sel == 1) { W = W1; bias = bias1; outB = o1; }
    else if (sel == 2) { W = W2; bias = bias2; outB = o2; }
  } else {
    W = W0 + ((size_t)(m0 >> 12) << 20);    // per-batch M_b (1M elems each)
  }
  int nloc0 = (MODE == 1) ? (n0 & 1023) : n0;

  int t = threadIdx.x, w = t >> 6, l = t & 63;
  int wm = w >> 2, wn = w & 3;              // 2M x 4N waves

  // ---- staging per-thread constants (2 x 16B units per granule) ----
  int u0 = t, u1 = t + 512;
  int lr0 = u0 >> 3, lr1 = u1 >> 3;
  int sl0 = (u0 & 7) ^ (lr0 & 7), sl1 = (u1 & 7) ^ (lr1 & 7);  // inverse-swizzled src slot
  int rA0 = ((lr0 >> 6) << 7) + (lr0 & 63), rA1 = ((lr1 >> 6) << 7) + (lr1 & 63);
  int rB0 = ((lr0 >> 5) << 6) + (lr0 & 31), rB1 = ((lr1 >> 5) << 6) + (lr1 & 31);
  const unsigned short* gA_0 = A + (size_t)(m0 + rA0) * 1024 + sl0 * 8;
  const unsigned short* gA_1 = A + (size_t)(m0 + rA1) * 1024 + sl1 * 8;
  const unsigned short* gB_0 = W + (size_t)(nloc0 + rB0) * 1024 + sl0 * 8;
  const unsigned short* gB_1 = W + (size_t)(nloc0 + rB1) * 1024 + sl1 * 8;

  // ---- reader constants ----
  int aRd = (wm * 64 + (l & 15)) * 128;
  int bRd = (wn * 32 + (l & 15)) * 128;
  int sr0 = (((l >> 4) + 0) ^ (l & 7)) * 16;  // ks=0 swizzled slot
  int sr1 = (((l >> 4) + 4) ^ (l & 7)) * 16;  // ks=1

  f32x4 acc[8][4];
  f32x4 zero = {0.f, 0.f, 0.f, 0.f};
#pragma unroll
  for (int i = 0; i < 8; ++i)
#pragma unroll
    for (int jx = 0; jx < 4; ++jx) acc[i][jx] = zero;
  bf16x8 af[4][2], bf0[2][2], bf1[2][2];

  // ---- prologue: tile0 (4 granules) + tile1 (A-g0, B-g0) ----
  STAGE_A(0, 0, 0); STAGE_B(0, 0, 0); STAGE_A(0, 1, 0); STAGE_B(0, 1, 0);
  STAGE_A(1, 0, 1); STAGE_B(1, 0, 1);
  WAITV4();   // tile0 fully landed (2 granules of tile1 in flight)
  BARX();

  for (int j = 0; j < 8; ++j) {
    int t1 = 2 * j + 1;
    int t2 = (j < 7) ? (2 * j + 2) : 14;  // last iter: re-stage L2-hot tiles
    int t3 = (j < 7) ? (2 * j + 3) : 15;  // (identical bytes -> benign)
    // P1
    LOAD_A(0, 0); LOAD_B(0, 0, bf0); LOAD_B(0, 1, bf1);
    STAGE_A(1, 1, t1); STAGE_B(1, 1, t1);
    P1(); QUAD(0, 0, bf0); QUAD(0, 1, bf1); P0();
    LOAD_A(0, 1);                         // tail: feeds P2
    LGKM0(); BARX();
    // P2
    STAGE_A(0, 0, t2); STAGE_B(0, 0, t2);
    P1(); QUAD(1, 0, bf0); QUAD(1, 1, bf1); P0();
    LGKM0(); WAITV4(); BARX();
    // P3
    LOAD_A(1, 0); LOAD_B(1, 0, bf0); LOAD_B(1, 1, bf1);
    STAGE_A(0, 1, t2); STAGE_B(0, 1, t2);
    P1(); QUAD(0, 0, bf0); QUAD(0, 1, bf1); P0();
    LOAD_A(1, 1);                         // tail: feeds P4
    LGKM0(); BARX();
    // P4
    STAGE_A(1, 0, t3); STAGE_B(1, 0, t3);
    P1(); QUAD(1, 0, bf0); QUAD(1, 1, bf1); P0();
    LGKM0(); WAITV4(); BARX();
  }
  WAITV0();  // drain all gl16 before epilogue overwrites sAB
  BARX();    // ...and make that drain visible workgroup-wide

  // ---- epilogue ----
  if (MODE == 1 && sel >= 1) {
    // k/v: write TRANSPOSED [bh][d][n] via in-LDS 256x256 transpose.
    int b_idx = m0 >> 12;
    int nloc_h = nloc0 >> 6;
    // pass A: acc -> LDS (col-major rows, XOR-swizzled)
#pragma unroll
    for (int mq = 0; mq < 8; ++mq) {
      int r_base = wm * 128 + (mq >> 2) * 64 + (mq & 3) * 16 + ((l >> 4) << 2);
#pragma unroll
      for (int nq = 0; nq < 4; ++nq) {
        int c_loc = wn * 64 + (nq >> 1) * 32 + (nq & 1) * 16 + (l & 15);
        float bb = bias[nloc0 + c_loc];
        float v0 = acc[mq][nq][0] + bb, v1 = acc[mq][nq][1] + bb;
        float v2 = acc[mq][nq][2] + bb, v3 = acc[mq][nq][3] + bb;
        if (sel == 1) {  // elu(x)+1 for k
          v0 = (v0 > 0.0f) ? (v0 + 1.0f) : __expf(v0);
          v1 = (v1 > 0.0f) ? (v1 + 1.0f) : __expf(v1);
          v2 = (v2 > 0.0f) ? (v2 + 1.0f) : __expf(v2);
          v3 = (v3 > 0.0f) ? (v3 + 1.0f) : __expf(v3);
        }
        unsigned long long pk =
            (unsigned long long)(f2b(v0) | ((unsigned int)f2b(v1) << 16)) |
            ((unsigned long long)(f2b(v2) | ((unsigned int)f2b(v3) << 16)) << 32);
        int byte = c_loc * 512 + ((r_base * 2) ^ ((c_loc & 7) << 4));
        *(unsigned long long*)(sAB + byte) = pk;
      }
    }
    __syncthreads();
    // pass B (COALESCED): half-wave = one 512B row-chunk, stored contiguously.
#pragma unroll
    for (int qq = 0; qq < 16; ++qq) {
      int c_loc = qq * 16 + w * 2 + (l >> 5);
      int n_off = (l & 31) * 8;
      int d = c_loc & 63;
      int bh = b_idx * 16 + nloc_h + (c_loc >> 6);
      int byte = c_loc * 512 + ((n_off * 2) ^ ((c_loc & 7) << 4));
      bf16x8 ch = *(const bf16x8*)(sAB + byte);
      *(bf16x8*)(outB + (size_t)(bh * 64 + d) * 4096 + (m0 & 4095) + n_off) = ch;
      if (sel == 1) {
        float s = 0.f;
#pragma unroll
        for (int jj = 0; jj < 8; ++jj) s += b2f((unsigned short)ch[jj]);
        s += __shfl_xor(s, 1);
        s += __shfl_xor(s, 2);
        s += __shfl_xor(s, 4);
        s += __shfl_xor(s, 8);
        s += __shfl_xor(s, 16);
        if ((l & 31) == 0) atomicAdd(ksum + bh * 64 + d, s);
      }
    }
  } else {
#pragma unroll
    for (int mq = 0; mq < 8; ++mq) {
      int grow = m0 + wm * 128 + (mq >> 2) * 64 + (mq & 3) * 16 + ((l >> 4) << 2);
#pragma unroll
      for (int nq = 0; nq < 4; ++nq) {
        int gcol = n0 + wn * 64 + (nq >> 1) * 32 + (nq & 1) * 16 + (l & 15);
        if (MODE == 0) {
          float bb = bias[gcol];
#pragma unroll
          for (int r = 0; r < 4; ++r)
            outF[(size_t)(grow + r) * 1024 + gcol] = acc[mq][nq][r] + bb;
        } else {  // sel == 0: q, row-major + elu+1
          int c = gcol & 1023;
          float bb = bias[c];
#pragma unroll
          for (int r = 0; r < 4; ++r) {
            float v = acc[mq][nq][r] + bb;
            v = (v > 0.0f) ? (v + 1.0f) : __expf(v);
            outB[(size_t)(grow + r) * 1024 + c] = f2b(v);
          }
        }
      }
    }
  }
}

// ---- MERGED: ctx partials (bid<512) + dinvq (bid 512..4607) ----
__global__ __launch_bounds__(256) void ctx_dinv_k(
    const unsigned short* __restrict__ kT,  // [bh][64][4096]
    const unsigned short* __restrict__ vT,  // [bh][64][4096]
    float* __restrict__ ctxP,               // [512][64][64] partials
    unsigned short* __restrict__ q,         // (16384,1024) in/out
    const float* __restrict__ ksum)         // [bh][64]
{
  __shared__ float red[4][64 * 65];  // padded
  int bid = blockIdx.x;
  int t = threadIdx.x, wv = t >> 6, l = t & 63;
  if (bid >= 512) {
    // ---- dinvq: q[n,hd] *= 1/(q[n,h,:].ksum + eps) ----
    int n = (bid - 512) * 4 + wv;
    int b = n >> 12;
    int h = l >> 2;
    unsigned short* qp = q + (size_t)n * 1024 + l * 16;
    const float* kp = ksum + (b * 16 + h) * 64 + (l & 3) * 16;
    bf16x8 v0 = *(const bf16x8*)qp;
    bf16x8 v1 = *(const bf16x8*)(qp + 8);
    float s = 0.f;
#pragma unroll
    for (int j = 0; j < 8; ++j) {
      s += b2f((unsigned short)v0[j]) * kp[j];
      s += b2f((unsigned short)v1[j]) * kp[8 + j];
    }
    s += __shfl_xor(s, 1);
    s += __shfl_xor(s, 2);
    float di = 1.0f / (s + 1e-6f);
#pragma unroll
    for (int j = 0; j < 8; ++j) {
      v0[j] = (short)f2b(b2f((unsigned short)v0[j]) * di);
      v1[j] = (short)f2b(b2f((unsigned short)v1[j]) * di);
    }
    *(bf16x8*)qp = v0;
    *(bf16x8*)(qp + 8) = v1;
    return;
  }
  // ---- ctx: ctxP[(bh*8+ch)][d][v] = sum over this chunk's n ----
  int bh = bid >> 3, ch = bid & 7;
  int noff = ch * 512 + wv * 128 + ((l >> 4) << 3);
  const unsigned short* aB = kT + ((size_t)bh * 64 + (l & 15)) * 4096 + noff;
  const unsigned short* bB = vT + ((size_t)bh * 64 + (l & 15)) * 4096 + noff;
  f32x4 acc[4][4];
  f32x4 zero = {0.f, 0.f, 0.f, 0.f};
#pragma unroll
  for (int i = 0; i < 4; ++i)
#pragma unroll
    for (int j = 0; j < 4; ++j) acc[i][j] = zero;
  for (int ks = 0; ks < 4; ++ks) {   // 4 x 32 n per wave = 128 n
    bf16x8 av[4], bv[4];
#pragma unroll
    for (int mi = 0; mi < 4; ++mi) av[mi] = *(const bf16x8*)(aB + (size_t)mi * 16 * 4096 + ks * 32);
#pragma unroll
    for (int ni = 0; ni < 4; ++ni) bv[ni] = *(const bf16x8*)(bB + (size_t)ni * 16 * 4096 + ks * 32);
#pragma unroll
    for (int mi = 0; mi < 4; ++mi)
#pragma unroll
      for (int ni = 0; ni < 4; ++ni)
        acc[mi][ni] = mfma16(av[mi], bv[ni], acc[mi][ni]);
  }
#pragma unroll
  for (int mi = 0; mi < 4; ++mi)
#pragma unroll
    for (int ni = 0; ni < 4; ++ni)
#pragma unroll
      for (int r = 0; r < 4; ++r) {
        int dd = mi * 16 + ((l >> 4) << 2) + r;   // k-dim
        int vv = ni * 16 + (l & 15);              // v-dim
        red[wv][dd * 65 + vv] = acc[mi][ni][r];
      }
  __syncthreads();
  for (int o = t; o < 4096; o += 256) {
    int idx = (o >> 6) * 65 + (o & 63);
    ctxP[(size_t)bid * 4096 + o] = red[0][idx] + red[1][idx] + red[2][idx] + red[3][idx];
  }
}

// ---- M_b[j][h*64+d] = sum_v ctx[b,h,d,v] * Wo[j, h*64+v] ----
__global__ __launch_bounds__(1024) void ctxwo_k(
    const float* __restrict__ ctxP,         // [512][64][64] partials
    const unsigned short* __restrict__ wo,  // [1024][1024] bf16
    unsigned short* __restrict__ M)         // [4][1024][1024] bf16
{
  __shared__ float cs[4096];
  int bh = blockIdx.x;
  int b = bh >> 4, h = bh & 15;
  int t = threadIdx.x, wv = t >> 6, l = t & 63;
  int j0 = wv * 64;

  // sum the 8 partials into LDS
  for (int o = t; o < 4096; o += 1024) {
    float s = 0.f;
#pragma unroll
    for (int ch = 0; ch < 8; ++ch) s += ctxP[((size_t)bh * 8 + ch) * 4096 + o];
    cs[o] = s;
  }
  __syncthreads();

  bf16x8 af[4][2], bf[4][2];
#pragma unroll
  for (int mi = 0; mi < 4; ++mi)
#pragma unroll
    for (int ks = 0; ks < 2; ++ks)
      af[mi][ks] = *(const bf16x8*)(wo + (size_t)(j0 + mi * 16 + (l & 15)) * 1024 +
                                    h * 64 + ((l >> 4) << 3) + ks * 32);
#pragma unroll
  for (int ni = 0; ni < 4; ++ni)
#pragma unroll
    for (int ks = 0; ks < 2; ++ks) {
      const float* p = cs + (ni * 16 + (l & 15)) * 64 + ((l >> 4) << 3) + ks * 32;
#pragma unroll
      for (int jj = 0; jj < 8; ++jj) bf[ni][ks][jj] = (short)f2b(p[jj]);
    }

  f32x4 acc[4][4];
  f32x4 zero = {0.f, 0.f, 0.f, 0.f};
#pragma unroll
  for (int i = 0; i < 4; ++i)
#pragma unroll
    for (int j = 0; j < 4; ++j) acc[i][j] = zero;
#pragma unroll
  for (int mi = 0; mi < 4; ++mi)
#pragma unroll
    for (int ni = 0; ni < 4; ++ni) {
      acc[mi][ni] = mfma16(af[mi][0], bf[ni][0], acc[mi][ni]);
      acc[mi][ni] = mfma16(af[mi][1], bf[ni][1], acc[mi][ni]);
    }

  unsigned short* Mb = M + ((size_t)b << 20);
#pragma unroll
  for (int mi = 0; mi < 4; ++mi)
#pragma unroll
    for (int ni = 0; ni < 4; ++ni)
#pragma unroll
      for (int r = 0; r < 4; ++r) {
        int j = j0 + mi * 16 + ((l >> 4) << 2) + r;
        int d = ni * 16 + (l & 15);
        Mb[(size_t)j * 1024 + h * 64 + d] = f2b(acc[mi][ni][r]);
      }
}

extern "C" void kernel_launch(void* const* d_in, const int* in_sizes, int n_in,
                              void* d_out, int out_size, void* d_ws, size_t ws_size,
                              hipStream_t stream)
{
  const float* x  = (const float*)d_in[0];
  const float* bq = (const float*)d_in[2];
  const float* bk = (const float*)d_in[4];
  const float* bv = (const float*)d_in[6];
  const float* bo = (const float*)d_in[8];
  const float* Wq = (const float*)d_in[1];
  const float* Wk = (const float*)d_in[3];
  const float* Wv = (const float*)d_in[5];
  const float* Wo = (const float*)d_in[7];
  float* out = (float*)d_out;

  char* ws = (char*)d_ws;
  const size_t SB = (size_t)16384 * 1024 * 2;  // 32 MiB slab
  const size_t NEED = 4 * SB + 4 * (1u << 21) + 2 * (1u << 20) + (1u << 14);
  if (ws_size < NEED) return;  // signature: absmax == max|ref| ~ 6.4e-2

  unsigned short* xb  = (unsigned short*)(ws);           // x bf16; dead after QKV
  unsigned short* qb  = (unsigned short*)(ws + SB);      // q bf16 (scaled in place)
  unsigned short* kTb = (unsigned short*)(ws + 2 * SB);  // kT [bh][d][n]
  unsigned short* vTb = (unsigned short*)(ws + 3 * SB);  // vT [bh][d][n]
  unsigned short* wqb = (unsigned short*)(ws + 4 * SB);
  unsigned short* wkb = (unsigned short*)(ws + 4 * SB + (1u << 21));
  unsigned short* wvb = (unsigned short*)(ws + 4 * SB + (2u << 21));
  unsigned short* wob = (unsigned short*)(ws + 4 * SB + (3u << 21));
  float* ksum = (float*)(ws + 4 * SB + (4u << 21) + (2u << 20));
  unsigned short* Mbuf = xb;                       // [4][1024][1024] bf16 = 8 MiB
  float* ctxP = (float*)(ws + (8u << 20));         // [512][4096] f32 = 8 MiB (in dead xb)

  cast_all<<<20481, 256, 0, stream>>>(x, Wq, Wk, Wv, Wo, xb, wqb, wkb, wvb, wob, ksum);

  // QKV: q row-major+elu, kT/vT transposed, ksum fused
  gemm256<1><<<768, 512, 0, stream>>>(xb, wqb, wkb, wvb, bq, bk, bv,
                                      nullptr, qb, kTb, vTb, 12, ksum);

  // ctx partials + q *= Dinv, one dispatch
  ctx_dinv_k<<<4608, 256, 0, stream>>>(kTb, vTb, ctxP, qb, ksum);

  ctxwo_k<<<64, 1024, 0, stream>>>(ctxP, wob, Mbuf);        // M_b = ctx @ Wo^T

  // final: out = q' @ M_b^T + bo  (per-batch weights)
  gemm256<0><<<256, 512, 0, stream>>>(qb, Mbuf, nullptr, nullptr, bo, nullptr, nullptr,
                                      out, nullptr, nullptr, nullptr, 4, nullptr);
}

// Round 16
// 214.170 us; speedup vs baseline: 1.0125x; 1.0125x over previous
//
#include <hip/hip_runtime.h>
#include <hip/hip_bf16.h>

typedef __attribute__((ext_vector_type(8))) short bf16x8;
typedef __attribute__((ext_vector_type(4))) float f32x4;

__device__ __forceinline__ float b2f(unsigned short u) {
  union { unsigned int i; float f; } x; x.i = ((unsigned int)u) << 16; return x.f;
}
__device__ __forceinline__ unsigned short f2b(float f) {
  union { __hip_bfloat16 h; unsigned short u; } x; x.h = __float2bfloat16(f); return x.u;
}
__device__ __forceinline__ f32x4 mfma16(bf16x8 a, bf16x8 b, f32x4 c) {
  return __builtin_amdgcn_mfma_f32_16x16x32_bf16(a, b, c, 0, 0, 0);
}
__device__ __forceinline__ void gl16(const void* g, void* l) {
  __builtin_amdgcn_global_load_lds(
      (const __attribute__((address_space(1))) unsigned int*)g,
      (__attribute__((address_space(3))) unsigned int*)l, 16, 0, 0);
}

// ---- ALL casts + ksum zero in ONE dispatch: x (16384 blks), 4 weights (4096), ksum (1) ----
__global__ __launch_bounds__(256) void cast_all(
    const float* __restrict__ x,
    const float* __restrict__ s0, const float* __restrict__ s1,
    const float* __restrict__ s2, const float* __restrict__ s3,
    unsigned short* __restrict__ xb,
    unsigned short* __restrict__ d0, unsigned short* __restrict__ d1,
    unsigned short* __restrict__ d2, unsigned short* __restrict__ d3,
    float* __restrict__ ksum) {
  int bid = blockIdx.x;
  if (bid < 16384) {
    int i = bid * 256 + threadIdx.x;
    float4 v = ((const float4*)x)[i];
    ushort4 o;
    o.x = f2b(v.x); o.y = f2b(v.y); o.z = f2b(v.z); o.w = f2b(v.w);
    ((ushort4*)xb)[i] = o;
  } else if (bid < 20480) {
    int r = bid - 16384;
    int seg = r >> 10;
    int i = (r & 1023) * 256 + threadIdx.x;
    const float* s = (seg == 0) ? s0 : (seg == 1) ? s1 : (seg == 2) ? s2 : s3;
    unsigned short* d = (seg == 0) ? d0 : (seg == 1) ? d1 : (seg == 2) ? d2 : d3;
    float4 v = ((const float4*)s)[i];
    ushort4 o;
    o.x = f2b(v.x); o.y = f2b(v.y); o.z = f2b(v.z); o.w = f2b(v.w);
    ((ushort4*)d)[i] = o;
  } else {
    ((float4*)ksum)[threadIdx.x * 4 + 0] = make_float4(0.f, 0.f, 0.f, 0.f);
    ((float4*)ksum)[threadIdx.x * 4 + 1] = make_float4(0.f, 0.f, 0.f, 0.f);
    ((float4*)ksum)[threadIdx.x * 4 + 2] = make_float4(0.f, 0.f, 0.f, 0.f);
    ((float4*)ksum)[threadIdx.x * 4 + 3] = make_float4(0.f, 0.f, 0.f, 0.f);
  }
}

// =============== 256x256 bf16 GEMM (C = A * W^T), K=1024 ===============
// R16 = CONSOLIDATION: exact R12 K-loop (best measured: 214.36us total,
// QKV 111.5us). Subsequent variants (R13 4-phase merge, R14/R15 LGKM0 move)
// were null-to-slightly-negative and are reverted. Structure: 8 phases/iter,
// ONE trailing barrier per phase (leading barrier removed -- QUAD reads
// registers; stage-after-read enforced by trailing-barrier chain, read-after-
// stage by WAITV4 at ph4/ph8 + trailing BARX). Tails in ph1/2/5/6 feed the
// next phase. vmcnt FIFO ledger identical to R4. Loop exit: WAITV0 + BARX.
#define BARX() __builtin_amdgcn_s_barrier()
#define LGKM0() asm volatile("s_waitcnt lgkmcnt(0)")
#define WAITV4() asm volatile("s_waitcnt vmcnt(4)")
#define WAITV0() asm volatile("s_waitcnt vmcnt(0)" ::: "memory")
#define P1() __builtin_amdgcn_s_setprio(1)
#define P0() __builtin_amdgcn_s_setprio(0)

#define STAGE_A(BUF, G, TAU) do { \
  gl16(gA_0 + (size_t)(G) * 65536 + (TAU) * 64, sAB + (BUF) * 32768 + (G) * 16384 + u0 * 16); \
  gl16(gA_1 + (size_t)(G) * 65536 + (TAU) * 64, sAB + (BUF) * 32768 + (G) * 16384 + u1 * 16); } while (0)
#define STAGE_B(BUF, G, TAU) do { \
  gl16(gB_0 + (size_t)(G) * 32768 + (TAU) * 64, sAB + 65536 + (BUF) * 32768 + (G) * 16384 + u0 * 16); \
  gl16(gB_1 + (size_t)(G) * 32768 + (TAU) * 64, sAB + 65536 + (BUF) * 32768 + (G) * 16384 + u1 * 16); } while (0)

#define LOAD_A(BUF, MH) do { \
  _Pragma("unroll") for (int mi = 0; mi < 4; ++mi) { \
    const char* p_ = (const char*)sAB + (BUF) * 32768 + (MH) * 16384 + aRd + mi * 2048; \
    af[mi][0] = *(const bf16x8*)(p_ + sr0); \
    af[mi][1] = *(const bf16x8*)(p_ + sr1); } } while (0)
#define LOAD_B(BUF, NH, DST) do { \
  _Pragma("unroll") for (int ni = 0; ni < 2; ++ni) { \
    const char* p_ = (const char*)sAB + 65536 + (BUF) * 32768 + (NH) * 16384 + bRd + ni * 2048; \
    DST[ni][0] = *(const bf16x8*)(p_ + sr0); \
    DST[ni][1] = *(const bf16x8*)(p_ + sr1); } } while (0)

#define QUAD(MH, NH, BF) do { \
  _Pragma("unroll") for (int mi = 0; mi < 4; ++mi) \
    _Pragma("unroll") for (int ni = 0; ni < 2; ++ni) { \
      acc[(MH) * 4 + mi][(NH) * 2 + ni] = mfma16(af[mi][0], BF[ni][0], acc[(MH) * 4 + mi][(NH) * 2 + ni]); \
      acc[(MH) * 4 + mi][(NH) * 2 + ni] = mfma16(af[mi][1], BF[ni][1], acc[(MH) * 4 + mi][(NH) * 2 + ni]); } } while (0)

template<int MODE>
__global__ __launch_bounds__(512, 2) void gemm256(
    const unsigned short* __restrict__ A,
    const unsigned short* __restrict__ W0, const unsigned short* __restrict__ W1,
    const unsigned short* __restrict__ W2,
    const float* __restrict__ bias0, const float* __restrict__ bias1, const float* __restrict__ bias2,
    float* __restrict__ outF,
    unsigned short* __restrict__ o0, unsigned short* __restrict__ o1, unsigned short* __restrict__ o2,
    int tiles_n, float* __restrict__ ksum)
{
  __shared__ char sAB[131072];
  int bid = blockIdx.x;
  int nwg = gridDim.x;
  int cpx = nwg >> 3;                       // nwg % 8 == 0 for all launches
  int sbid = (bid & 7) * cpx + (bid >> 3);  // XCD-aware swizzle (bijective)
  int tn = sbid % tiles_n, tm = sbid / tiles_n;  // tm-major within XCD
  int m0 = tm * 256, n0 = tn * 256;

  const unsigned short* W = W0; const float* bias = bias0; unsigned short* outB = o0;
  int sel = 0;
  if (MODE == 1) {
    sel = n0 >> 10;
    if (sel == 1) { W = W1; bias = bias1; outB = o1; }
    else if (sel == 2) { W = W2; bias = bias2; outB = o2; }
  } else {
    W = W0 + ((size_t)(m0 >> 12) << 20);    // per-batch M_b (1M elems each)
  }
  int nloc0 = (MODE == 1) ? (n0 & 1023) : n0;

  int t = threadIdx.x, w = t >> 6, l = t & 63;
  int wm = w >> 2, wn = w & 3;              // 2M x 4N waves

  // ---- staging per-thread constants (2 x 16B units per granule) ----
  int u0 = t, u1 = t + 512;
  int lr0 = u0 >> 3, lr1 = u1 >> 3;
  int sl0 = (u0 & 7) ^ (lr0 & 7), sl1 = (u1 & 7) ^ (lr1 & 7);  // inverse-swizzled src slot
  int rA0 = ((lr0 >> 6) << 7) + (lr0 & 63), rA1 = ((lr1 >> 6) << 7) + (lr1 & 63);
  int rB0 = ((lr0 >> 5) << 6) + (lr0 & 31), rB1 = ((lr1 >> 5) << 6) + (lr1 & 31);
  const unsigned short* gA_0 = A + (size_t)(m0 + rA0) * 1024 + sl0 * 8;
  const unsigned short* gA_1 = A + (size_t)(m0 + rA1) * 1024 + sl1 * 8;
  const unsigned short* gB_0 = W + (size_t)(nloc0 + rB0) * 1024 + sl0 * 8;
  const unsigned short* gB_1 = W + (size_t)(nloc0 + rB1) * 1024 + sl1 * 8;

  // ---- reader constants ----
  int aRd = (wm * 64 + (l & 15)) * 128;
  int bRd = (wn * 32 + (l & 15)) * 128;
  int sr0 = (((l >> 4) + 0) ^ (l & 7)) * 16;  // ks=0 swizzled slot
  int sr1 = (((l >> 4) + 4) ^ (l & 7)) * 16;  // ks=1

  f32x4 acc[8][4];
  f32x4 zero = {0.f, 0.f, 0.f, 0.f};
#pragma unroll
  for (int i = 0; i < 8; ++i)
#pragma unroll
    for (int jx = 0; jx < 4; ++jx) acc[i][jx] = zero;
  bf16x8 af[4][2], bf0[2][2], bf1[2][2];

  // ---- prologue: tile0 (4 granules) + tile1 (A-g0, B-g0) ----
  STAGE_A(0, 0, 0); STAGE_B(0, 0, 0); STAGE_A(0, 1, 0); STAGE_B(0, 1, 0);
  STAGE_A(1, 0, 1); STAGE_B(1, 0, 1);
  WAITV4();   // tile0 fully landed (2 granules of tile1 in flight)
  BARX();

  for (int j = 0; j < 8; ++j) {
    int t1 = 2 * j + 1;
    int t2 = (j < 7) ? (2 * j + 2) : 14;  // last iter: re-stage L2-hot tiles
    int t3 = (j < 7) ? (2 * j + 3) : 15;  // (identical bytes -> benign)
    // ph1
    LOAD_A(0, 0); LOAD_B(0, 0, bf0);
    STAGE_A(1, 1, t1);
    LGKM0(); P1(); QUAD(0, 0, bf0); P0();
    LOAD_B(0, 1, bf1);                    // tail: feeds ph2
    BARX();
    // ph2
    STAGE_B(1, 1, t1);
    LGKM0(); P1(); QUAD(0, 1, bf1); P0();
    LOAD_A(0, 1);                         // tail: feeds ph3
    BARX();
    // ph3
    STAGE_A(0, 0, t2);
    LGKM0(); P1(); QUAD(1, 0, bf0); P0(); BARX();
    // ph4
    STAGE_B(0, 0, t2);
    LGKM0(); P1(); QUAD(1, 1, bf1); P0(); WAITV4(); BARX();
    // ph5
    LOAD_A(1, 0); LOAD_B(1, 0, bf0);
    STAGE_A(0, 1, t2);
    LGKM0(); P1(); QUAD(0, 0, bf0); P0();
    LOAD_B(1, 1, bf1);                    // tail: feeds ph6
    BARX();
    // ph6
    STAGE_B(0, 1, t2);
    LGKM0(); P1(); QUAD(0, 1, bf1); P0();
    LOAD_A(1, 1);                         // tail: feeds ph7
    BARX();
    // ph7
    STAGE_A(1, 0, t3);
    LGKM0(); P1(); QUAD(1, 0, bf0); P0(); BARX();
    // ph8
    STAGE_B(1, 0, t3);
    LGKM0(); P1(); QUAD(1, 1, bf1); P0(); WAITV4(); BARX();
  }
  WAITV0();  // drain all gl16 before epilogue overwrites sAB
  BARX();    // ...and make that drain visible workgroup-wide

  // ---- epilogue ----
  if (MODE == 1 && sel >= 1) {
    // k/v: write TRANSPOSED [bh][d][n] via in-LDS 256x256 transpose.
    int b_idx = m0 >> 12;
    int nloc_h = nloc0 >> 6;
    // pass A: acc -> LDS (col-major rows, XOR-swizzled)
#pragma unroll
    for (int mq = 0; mq < 8; ++mq) {
      int r_base = wm * 128 + (mq >> 2) * 64 + (mq & 3) * 16 + ((l >> 4) << 2);
#pragma unroll
      for (int nq = 0; nq < 4; ++nq) {
        int c_loc = wn * 64 + (nq >> 1) * 32 + (nq & 1) * 16 + (l & 15);
        float bb = bias[nloc0 + c_loc];
        float v0 = acc[mq][nq][0] + bb, v1 = acc[mq][nq][1] + bb;
        float v2 = acc[mq][nq][2] + bb, v3 = acc[mq][nq][3] + bb;
        if (sel == 1) {  // elu(x)+1 for k
          v0 = (v0 > 0.0f) ? (v0 + 1.0f) : __expf(v0);
          v1 = (v1 > 0.0f) ? (v1 + 1.0f) : __expf(v1);
          v2 = (v2 > 0.0f) ? (v2 + 1.0f) : __expf(v2);
          v3 = (v3 > 0.0f) ? (v3 + 1.0f) : __expf(v3);
        }
        unsigned long long pk =
            (unsigned long long)(f2b(v0) | ((unsigned int)f2b(v1) << 16)) |
            ((unsigned long long)(f2b(v2) | ((unsigned int)f2b(v3) << 16)) << 32);
        int byte = c_loc * 512 + ((r_base * 2) ^ ((c_loc & 7) << 4));
        *(unsigned long long*)(sAB + byte) = pk;
      }
    }
    __syncthreads();
    // pass B (COALESCED): half-wave = one 512B row-chunk, stored contiguously.
#pragma unroll
    for (int qq = 0; qq < 16; ++qq) {
      int c_loc = qq * 16 + w * 2 + (l >> 5);
      int n_off = (l & 31) * 8;
      int d = c_loc & 63;
      int bh = b_idx * 16 + nloc_h + (c_loc >> 6);
      int byte = c_loc * 512 + ((n_off * 2) ^ ((c_loc & 7) << 4));
      bf16x8 ch = *(const bf16x8*)(sAB + byte);
      *(bf16x8*)(outB + (size_t)(bh * 64 + d) * 4096 + (m0 & 4095) + n_off) = ch;
      if (sel == 1) {
        float s = 0.f;
#pragma unroll
        for (int jj = 0; jj < 8; ++jj) s += b2f((unsigned short)ch[jj]);
        s += __shfl_xor(s, 1);
        s += __shfl_xor(s, 2);
        s += __shfl_xor(s, 4);
        s += __shfl_xor(s, 8);
        s += __shfl_xor(s, 16);
        if ((l & 31) == 0) atomicAdd(ksum + bh * 64 + d, s);
      }
    }
  } else {
#pragma unroll
    for (int mq = 0; mq < 8; ++mq) {
      int grow = m0 + wm * 128 + (mq >> 2) * 64 + (mq & 3) * 16 + ((l >> 4) << 2);
#pragma unroll
      for (int nq = 0; nq < 4; ++nq) {
        int gcol = n0 + wn * 64 + (nq >> 1) * 32 + (nq & 1) * 16 + (l & 15);
        if (MODE == 0) {
          float bb = bias[gcol];
#pragma unroll
          for (int r = 0; r < 4; ++r)
            outF[(size_t)(grow + r) * 1024 + gcol] = acc[mq][nq][r] + bb;
        } else {  // sel == 0: q, row-major + elu+1
          int c = gcol & 1023;
          float bb = bias[c];
#pragma unroll
          for (int r = 0; r < 4; ++r) {
            float v = acc[mq][nq][r] + bb;
            v = (v > 0.0f) ? (v + 1.0f) : __expf(v);
            outB[(size_t)(grow + r) * 1024 + c] = f2b(v);
          }
        }
      }
    }
  }
}

// ---- MERGED: ctx partials (bid<512) + dinvq (bid 512..4607) ----
__global__ __launch_bounds__(256) void ctx_dinv_k(
    const unsigned short* __restrict__ kT,  // [bh][64][4096]
    const unsigned short* __restrict__ vT,  // [bh][64][4096]
    float* __restrict__ ctxP,               // [512][64][64] partials
    unsigned short* __restrict__ q,         // (16384,1024) in/out
    const float* __restrict__ ksum)         // [bh][64]
{
  __shared__ float red[4][64 * 65];  // padded
  int bid = blockIdx.x;
  int t = threadIdx.x, wv = t >> 6, l = t & 63;
  if (bid >= 512) {
    // ---- dinvq: q[n,hd] *= 1/(q[n,h,:].ksum + eps) ----
    int n = (bid - 512) * 4 + wv;
    int b = n >> 12;
    int h = l >> 2;
    unsigned short* qp = q + (size_t)n * 1024 + l * 16;
    const float* kp = ksum + (b * 16 + h) * 64 + (l & 3) * 16;
    bf16x8 v0 = *(const bf16x8*)qp;
    bf16x8 v1 = *(const bf16x8*)(qp + 8);
    float s = 0.f;
#pragma unroll
    for (int j = 0; j < 8; ++j) {
      s += b2f((unsigned short)v0[j]) * kp[j];
      s += b2f((unsigned short)v1[j]) * kp[8 + j];
    }
    s += __shfl_xor(s, 1);
    s += __shfl_xor(s, 2);
    float di = 1.0f / (s + 1e-6f);
#pragma unroll
    for (int j = 0; j < 8; ++j) {
      v0[j] = (short)f2b(b2f((unsigned short)v0[j]) * di);
      v1[j] = (short)f2b(b2f((unsigned short)v1[j]) * di);
    }
    *(bf16x8*)qp = v0;
    *(bf16x8*)(qp + 8) = v1;
    return;
  }
  // ---- ctx: ctxP[(bh*8+ch)][d][v] = sum over this chunk's n ----
  int bh = bid >> 3, ch = bid & 7;
  int noff = ch * 512 + wv * 128 + ((l >> 4) << 3);
  const unsigned short* aB = kT + ((size_t)bh * 64 + (l & 15)) * 4096 + noff;
  const unsigned short* bB = vT + ((size_t)bh * 64 + (l & 15)) * 4096 + noff;
  f32x4 acc[4][4];
  f32x4 zero = {0.f, 0.f, 0.f, 0.f};
#pragma unroll
  for (int i = 0; i < 4; ++i)
#pragma unroll
    for (int j = 0; j < 4; ++j) acc[i][j] = zero;
  for (int ks = 0; ks < 4; ++ks) {   // 4 x 32 n per wave = 128 n
    bf16x8 av[4], bv[4];
#pragma unroll
    for (int mi = 0; mi < 4; ++mi) av[mi] = *(const bf16x8*)(aB + (size_t)mi * 16 * 4096 + ks * 32);
#pragma unroll
    for (int ni = 0; ni < 4; ++ni) bv[ni] = *(const bf16x8*)(bB + (size_t)ni * 16 * 4096 + ks * 32);
#pragma unroll
    for (int mi = 0; mi < 4; ++mi)
#pragma unroll
      for (int ni = 0; ni < 4; ++ni)
        acc[mi][ni] = mfma16(av[mi], bv[ni], acc[mi][ni]);
  }
#pragma unroll
  for (int mi = 0; mi < 4; ++mi)
#pragma unroll
    for (int ni = 0; ni < 4; ++ni)
#pragma unroll
      for (int r = 0; r < 4; ++r) {
        int dd = mi * 16 + ((l >> 4) << 2) + r;   // k-dim
        int vv = ni * 16 + (l & 15);              // v-dim
        red[wv][dd * 65 + vv] = acc[mi][ni][r];
      }
  __syncthreads();
  for (int o = t; o < 4096; o += 256) {
    int idx = (o >> 6) * 65 + (o & 63);
    ctxP[(size_t)bid * 4096 + o] = red[0][idx] + red[1][idx] + red[2][idx] + red[3][idx];
  }
}

// ---- M_b[j][h*64+d] = sum_v ctx[b,h,d,v] * Wo[j, h*64+v] ----
__global__ __launch_bounds__(1024) void ctxwo_k(
    const float* __restrict__ ctxP,         // [512][64][64] partials
    const unsigned short* __restrict__ wo,  // [1024][1024] bf16
    unsigned short* __restrict__ M)         // [4][1024][1024] bf16
{
  __shared__ float cs[4096];
  int bh = blockIdx.x;
  int b = bh >> 4, h = bh & 15;
  int t = threadIdx.x, wv = t >> 6, l = t & 63;
  int j0 = wv * 64;

  // sum the 8 partials into LDS
  for (int o = t; o < 4096; o += 1024) {
    float s = 0.f;
#pragma unroll
    for (int ch = 0; ch < 8; ++ch) s += ctxP[((size_t)bh * 8 + ch) * 4096 + o];
    cs[o] = s;
  }
  __syncthreads();

  bf16x8 af[4][2], bf[4][2];
#pragma unroll
  for (int mi = 0; mi < 4; ++mi)
#pragma unroll
    for (int ks = 0; ks < 2; ++ks)
      af[mi][ks] = *(const bf16x8*)(wo + (size_t)(j0 + mi * 16 + (l & 15)) * 1024 +
                                    h * 64 + ((l >> 4) << 3) + ks * 32);
#pragma unroll
  for (int ni = 0; ni < 4; ++ni)
#pragma unroll
    for (int ks = 0; ks < 2; ++ks) {
      const float* p = cs + (ni * 16 + (l & 15)) * 64 + ((l >> 4) << 3) + ks * 32;
#pragma unroll
      for (int jj = 0; jj < 8; ++jj) bf[ni][ks][jj] = (short)f2b(p[jj]);
    }

  f32x4 acc[4][4];
  f32x4 zero = {0.f, 0.f, 0.f, 0.f};
#pragma unroll
  for (int i = 0; i < 4; ++i)
#pragma unroll
    for (int j = 0; j < 4; ++j) acc[i][j] = zero;
#pragma unroll
  for (int mi = 0; mi < 4; ++mi)
#pragma unroll
    for (int ni = 0; ni < 4; ++ni) {
      acc[mi][ni] = mfma16(af[mi][0], bf[ni][0], acc[mi][ni]);
      acc[mi][ni] = mfma16(af[mi][1], bf[ni][1], acc[mi][ni]);
    }

  unsigned short* Mb = M + ((size_t)b << 20);
#pragma unroll
  for (int mi = 0; mi < 4; ++mi)
#pragma unroll
    for (int ni = 0; ni < 4; ++ni)
#pragma unroll
      for (int r = 0; r < 4; ++r) {
        int j = j0 + mi * 16 + ((l >> 4) << 2) + r;
        int d = ni * 16 + (l & 15);
        Mb[(size_t)j * 1024 + h * 64 + d] = f2b(acc[mi][ni][r]);
      }
}

extern "C" void kernel_launch(void* const* d_in, const int* in_sizes, int n_in,
                              void* d_out, int out_size, void* d_ws, size_t ws_size,
                              hipStream_t stream)
{
  const float* x  = (const float*)d_in[0];
  const float* bq = (const float*)d_in[2];
  const float* bk = (const float*)d_in[4];
  const float* bv = (const float*)d_in[6];
  const float* bo = (const float*)d_in[8];
  const float* Wq = (const float*)d_in[1];
  const float* Wk = (const float*)d_in[3];
  const float* Wv = (const float*)d_in[5];
  const float* Wo = (const float*)d_in[7];
  float* out = (float*)d_out;

  char* ws = (char*)d_ws;
  const size_t SB = (size_t)16384 * 1024 * 2;  // 32 MiB slab
  const size_t NEED = 4 * SB + 4 * (1u << 21) + 2 * (1u << 20) + (1u << 14);
  if (ws_size < NEED) return;  // signature: absmax == max|ref| ~ 6.4e-2

  unsigned short* xb  = (unsigned short*)(ws);           // x bf16; dead after QKV
  unsigned short* qb  = (unsigned short*)(ws + SB);      // q bf16 (scaled in place)
  unsigned short* kTb = (unsigned short*)(ws + 2 * SB);  // kT [bh][d][n]
  unsigned short* vTb = (unsigned short*)(ws + 3 * SB);  // vT [bh][d][n]
  unsigned short* wqb = (unsigned short*)(ws + 4 * SB);
  unsigned short* wkb = (unsigned short*)(ws + 4 * SB + (1u << 21));
  unsigned short* wvb = (unsigned short*)(ws + 4 * SB + (2u << 21));
  unsigned short* wob = (unsigned short*)(ws + 4 * SB + (3u << 21));
  float* ksum = (float*)(ws + 4 * SB + (4u << 21) + (2u << 20));
  unsigned short* Mbuf = xb;                       // [4][1024][1024] bf16 = 8 MiB
  float* ctxP = (float*)(ws + (8u << 20));         // [512][4096] f32 = 8 MiB (in dead xb)

  cast_all<<<20481, 256, 0, stream>>>(x, Wq, Wk, Wv, Wo, xb, wqb, wkb, wvb, wob, ksum);

  // QKV: q row-major+elu, kT/vT transposed, ksum fused
  gemm256<1><<<768, 512, 0, stream>>>(xb, wqb, wkb, wvb, bq, bk, bv,
                                      nullptr, qb, kTb, vTb, 12, ksum);

  // ctx partials + q *= Dinv, one dispatch
  ctx_dinv_k<<<4608, 256, 0, stream>>>(kTb, vTb, ctxP, qb, ksum);

  ctxwo_k<<<64, 1024, 0, stream>>>(ctxP, wob, Mbuf);        // M_b = ctx @ Wo^T

  // final: out = q' @ M_b^T + bo  (per-batch weights)
  gemm256<0><<<256, 512, 0, stream>>>(qb, Mbuf, nullptr, nullptr, bo, nullptr, nullptr,
                                      out, nullptr, nullptr, nullptr, 4, nullptr);
}